// Round 1
// baseline (75.994 us; speedup 1.0000x reference)
//
#include <hip/hip_runtime.h>
#include <math.h>
#include <float.h>

#define D 64
#define K 15
#define S 120          // K*(K+1)/2
#define MNUM 100
#define C0 (-58.81206612509905f)   // -0.5 * 64 * log(2*pi)
#define L2E 1.4426950408889634f
#define INV_L2E 0.6931471805599453f
#define LOGM 4.605170185988091f    // log(100)

static __device__ __forceinline__ float fexp2(float x) {
    return __builtin_amdgcn_exp2f(x);
}

// Single fused kernel: per-block redundant setup (softmax(pi) + per-edge
// quadratics, ~23k FMAs/block -- trivial), then one wave per sample,
// block-aggregated atomicAdd into the scalar output.
// Rationale: the 3-kernel chain paid 2 single-block dispatch bubbles that
// dwarfed the ~5us of real compute.
__global__ __launch_bounds__(256) void gmm_fused(const float* __restrict__ z,
                                                 const float* __restrict__ pi,
                                                 const float* __restrict__ mu,
                                                 float* __restrict__ out) {
    __shared__ float mush[D * K];          // mu staged: mu[d*K+k]
    __shared__ float G0[S], G1[S], G2[S];  // per-edge quadratic coeffs
    __shared__ unsigned char iA[S], iB[S];
    __shared__ float zsh[4][D];
    __shared__ float red[4];
    __shared__ float bsum[4];

    const int t = threadIdx.x;
    const int lane = t & 63;
    const int wv = t >> 6;

    // ---- stage mu into LDS (coalesced; reused by setup AND c[k] dot) ----
    for (int i = t; i < D * K; i += 256) mush[i] = mu[i];

    // ---- softmax(pi) over 120 entries (block reduce across 4 waves) ----
    float p = (t < S) ? pi[t] : -FLT_MAX;
    float mx = p;
    #pragma unroll
    for (int off = 32; off; off >>= 1) mx = fmaxf(mx, __shfl_xor(mx, off));
    if (lane == 0) red[wv] = mx;
    __syncthreads();                                   // red(max) + mush ready
    mx = fmaxf(fmaxf(red[0], red[1]), fmaxf(red[2], red[3]));

    float e = (t < S) ? __expf(p - mx) : 0.f;
    float se = e;
    #pragma unroll
    for (int off = 32; off; off >>= 1) se += __shfl_xor(se, off);
    __syncthreads();                                   // done reading red(max)
    if (lane == 0) red[wv] = se;
    __syncthreads();
    se = red[0] + red[1] + red[2] + red[3];

    // ---- per-edge quadratics: thread t handles edge s = t (t < 120) ----
    if (t < S) {
        float sm = e / se;
        float logpi = logf(sm + 1e-30f);   // matches ref's log(softmax + 1e-30)

        int i = 0, rem = t;
        while (rem >= K - i) { rem -= K - i; ++i; }
        int j = i + rem;

        float aa = 0.f, ab = 0.f, bb = 0.f;
        #pragma unroll 8
        for (int d = 0; d < D; ++d) {
            float ma = mush[d * K + i];
            float mb = mush[d * K + j];
            aa = fmaf(ma, ma, aa);
            ab = fmaf(ma, mb, ab);
            bb = fmaf(mb, mb, bb);
        }
        float q0 = bb;
        float q1 = 2.f * (ab - bb);
        float q2 = aa - 2.f * ab + bb;

        G0[t] = C0 + logpi - 0.5f * q0;
        G1[t] = -0.5f * q1;
        G2[t] = -0.5f * q2;       // == -0.5*||muA-muB||^2 <= 0 (concave in w)
        iA[t] = (unsigned char)i;
        iB[t] = (unsigned char)j;
    }

    // ---- z + ||z||^2 (one wave per sample; xor-reduce so all lanes get zz) ----
    const int b = (blockIdx.x << 2) + wv;
    float zval = z[b * D + lane];
    zsh[wv][lane] = zval;
    float zz = zval * zval;
    #pragma unroll
    for (int off = 32; off; off >>= 1) zz += __shfl_xor(zz, off);
    __syncthreads();                           // G*, iA/iB, zsh all visible

    // ---- c[k] = z_b . mu[:,k]; group g covers 16 d's for k = lane&15 ----
    const int g = lane >> 4;
    const int kk = lane & 15;
    const int kkc = (kk < K) ? kk : (K - 1);
    const float* zw = &zsh[wv][g * 16];
    float cpart = 0.f;
    #pragma unroll
    for (int i = 0; i < 16; ++i)
        cpart = fmaf(zw[i], mush[(g * 16 + i) * K + kkc], cpart);
    cpart += __shfl_xor(cpart, 16);
    cpart += __shfl_xor(cpart, 32);
    // lanes 0..14 hold c[0..14]

    // ---- per-s quadratics: s1 = lane, s2 = lane+64 (valid for lane<56) ----
    const int s1 = lane;
    const int s2 = lane + 64;
    const bool v2 = (s2 < S);
    const int s2c = v2 ? s2 : (S - 1);

    float cA1 = __shfl(cpart, (int)iA[s1]);
    float cB1 = __shfl(cpart, (int)iB[s1]);
    float cA2 = __shfl(cpart, (int)iA[s2c]);
    float cB2 = __shfl(cpart, (int)iB[s2c]);

    float T01 = G0[s1] + cB1 - 0.5f * zz;
    float T11 = G1[s1] + (cA1 - cB1);
    float T21 = G2[s1];
    float T02 = v2 ? (G0[s2c] + cB2 - 0.5f * zz) : -1e30f;
    float T12 = G1[s2c] + (cA2 - cB2);
    float T22 = G2[s2c];

    // analytic max bound over w in [0, 0.99] (quadratics are concave: T2 <= 0)
    float bnd = fmaxf(T01, fmaf(0.99f, fmaf(0.99f, T21, T11), T01));
    if (T21 < 0.f) {
        float wv1 = fminf(fmaxf(-T11 * 0.5f * __builtin_amdgcn_rcpf(T21), 0.f), 0.99f);
        bnd = fmaxf(bnd, fmaf(wv1, fmaf(wv1, T21, T11), T01));
    }
    if (v2) {
        float b2 = fmaxf(T02, fmaf(0.99f, fmaf(0.99f, T22, T12), T02));
        if (T22 < 0.f) {
            float wv2 = fminf(fmaxf(-T12 * 0.5f * __builtin_amdgcn_rcpf(T22), 0.f), 0.99f);
            b2 = fmaxf(b2, fmaf(wv2, fmaf(wv2, T22, T12), T02));
        }
        bnd = fmaxf(bnd, b2);
    }
    #pragma unroll
    for (int off = 32; off; off >>= 1) bnd = fmaxf(bnd, __shfl_xor(bnd, off));
    const float Mb = bnd;

    // ---- log2-domain coefficients (a0 includes -Mb) ----
    const float a01 = (T01 - Mb) * L2E, a11 = T11 * L2E, a21 = T21 * L2E;
    const float a02 = (T02 - Mb) * L2E, a12 = T12 * L2E, a22 = T22 * L2E;

    // Multiplicative recurrence, initialized at w=0.5 (m=50), run outward.
    // e_{m+1}/e_m = exp2(a1*d + a2*d^2*(2m+1)), ratio-of-ratios h = exp2(2*a2*d^2).
    // Concavity (a2<=0) => outward decay is monotone past the vertex, so
    // flush-to-zero only loses negligible terms; init at mid is within
    // |a2|/4 log2-units of the peak (no spurious underflow).
    float e1  = fexp2(fmaf(0.5f, fmaf(0.5f, a21, a11), a01));  // e at m=50
    float g1  = fexp2(fmaf(0.0101f, a21,  0.01f * a11));       // e51/e50
    float dd1 = fexp2(fmaf(-0.0099f, a21, -0.01f * a11));      // e49/e50
    float h1  = fexp2(2.0e-4f * a21);

    float e2  = fexp2(fmaf(0.5f, fmaf(0.5f, a22, a12), a02));
    float g2  = fexp2(fmaf(0.0101f, a22,  0.01f * a12));
    float dd2 = fexp2(fmaf(-0.0099f, a22, -0.01f * a12));
    float h2  = fexp2(2.0e-4f * a22);

    float eu1 = e1,        gu1 = g1;
    float ed1 = e1 * dd1,  du1 = dd1 * h1;
    float eu2 = e2,        gu2 = g2;
    float ed2 = e2 * dd2,  du2 = dd2 * h2;
    float su1 = 0.f, sd1 = 0.f, su2 = 0.f, sd2 = 0.f;

    #pragma unroll 10
    for (int m = 0; m < 50; ++m) {
        su1 += eu1; eu1 *= gu1; gu1 *= h1;   // e_50 .. e_99
        sd1 += ed1; ed1 *= du1; du1 *= h1;   // e_49 .. e_0
        su2 += eu2; eu2 *= gu2; gu2 *= h2;
        sd2 += ed2; ed2 *= du2; du2 *= h2;
    }

    float ssum = (su1 + sd1) + (su2 + sd2);
    #pragma unroll
    for (int off = 32; off; off >>= 1) ssum += __shfl_xor(ssum, off);

    // ---- block aggregation: 4 lse values -> one atomicAdd ----
    if (lane == 0)
        bsum[wv] = Mb + __builtin_amdgcn_logf(ssum) * INV_L2E;
    __syncthreads();
    if (t == 0) {
        float blk = ((bsum[0] + bsum[1]) + (bsum[2] + bsum[3]) - 4.f * LOGM)
                    * (1.0f / 4096.0f);
        atomicAdd(out, blk);
    }
}

extern "C" void kernel_launch(void* const* d_in, const int* in_sizes, int n_in,
                              void* d_out, int out_size, void* d_ws, size_t ws_size,
                              hipStream_t stream) {
    const float* z  = (const float*)d_in[0];   // [4096, 1, 64]
    const float* pi = (const float*)d_in[1];   // [1, 120]
    const float* mu = (const float*)d_in[2];   // [64, 15]
    float* out = (float*)d_out;                // scalar

    hipMemsetAsync(out, 0, sizeof(float), stream);  // graph-capturable memset node
    gmm_fused<<<1024, 256, 0, stream>>>(z, pi, mu, out);
}

// Round 2
// 70.009 us; speedup vs baseline: 1.0855x; 1.0855x over previous
//
#include <hip/hip_runtime.h>
#include <math.h>
#include <float.h>

#define D 64
#define K 15
#define S 120          // K*(K+1)/2
#define MNUM 100
#define C0 (-58.81206612509905f)   // -0.5 * 64 * log(2*pi)
#define L2E 1.4426950408889634f
#define INV_L2E 0.6931471805599453f
#define LOGM 4.605170185988091f    // log(100)

static __device__ __forceinline__ float fexp2(float x) { return __builtin_amdgcn_exp2f(x); }
static __device__ __forceinline__ float flog2(float x) { return __builtin_amdgcn_logf(x); }

// Concave quadratic max over w in [0, 0.99]: T0 + T1*w + T2*w^2, T2 <= 0.
static __device__ __forceinline__ float qbound(float T0, float T1, float T2, float r2) {
    float bnd = fmaxf(T0, fmaf(0.99f, fmaf(0.99f, T2, T1), T0));
    if (T2 < 0.f) {
        float wx = fminf(fmaxf(-T1 * 0.5f * r2, 0.f), 0.99f);
        bnd = fmaxf(bnd, fmaf(wx, fmaf(wx, T2, T1), T0));
    }
    return bnd;
}

// Single fused kernel, 512 blocks x 256 threads, 2 samples per wave.
// vs previous: atomics 1024->512, redundant setups halved, setup shared
// across the wave's two samples (G loads, mush reads, T2, rcp, ratio h),
// shfl-only softmax (3 barriers -> 2), z loads hoisted.
__global__ __launch_bounds__(256) void gmm_fused(const float* __restrict__ z,
                                                 const float* __restrict__ pi,
                                                 const float* __restrict__ mu,
                                                 float* __restrict__ out) {
    __shared__ float mush[D * K];          // mu staged: mu[d*K+k]
    __shared__ float G0[S], G1[S], G2[S];  // per-edge quadratic coeffs
    __shared__ int   iA[S], iB[S];
    __shared__ float zsh[8][D];
    __shared__ float bsum[8];

    const int t = threadIdx.x;
    const int lane = t & 63;
    const int wv = t >> 6;
    const int b0 = (blockIdx.x << 3) + (wv << 1);   // wave handles b0, b0+1

    // ---- z loads issued first (HBM latency hides under staging/setup) ----
    float zv0 = z[b0 * D + lane];
    float zv1 = z[b0 * D + D + lane];

    // ---- stage mu into LDS ----
    for (int i = t; i < D * K; i += 256) mush[i] = mu[i];

    // ---- wave-private zsh store + ||z||^2 (no barrier needed: wave reads own rows) ----
    zsh[(wv << 1)][lane] = zv0;
    zsh[(wv << 1) + 1][lane] = zv1;
    float zz0 = zv0 * zv0, zz1 = zv1 * zv1;
    #pragma unroll
    for (int off = 32; off; off >>= 1) {
        zz0 += __shfl_xor(zz0, off);
        zz1 += __shfl_xor(zz1, off);
    }

    __syncthreads();                       // mush fully staged

    // ---- setup on waves 0-1 only: shfl-only softmax + per-edge quadratics ----
    if (t < 128) {
        float pa = pi[lane];                                   // s = lane (always < 120)
        float pb = (lane < S - 64) ? pi[lane + 64] : -FLT_MAX; // s = lane+64
        float mx = fmaxf(pa, pb);
        #pragma unroll
        for (int off = 32; off; off >>= 1) mx = fmaxf(mx, __shfl_xor(mx, off));
        float ea = fexp2((pa - mx) * L2E);
        float eb = (lane < S - 64) ? fexp2((pb - mx) * L2E) : 0.f;
        float se = ea + eb;
        #pragma unroll
        for (int off = 32; off; off >>= 1) se += __shfl_xor(se, off);

        if (t < S) {
            float e = wv ? eb : ea;            // wave0: s=lane, wave1: s=64+lane
            float logpi = logf(e / se + 1e-30f);  // matches ref log(softmax+1e-30)

            int i = 0, rem = t;
            while (rem >= K - i) { rem -= K - i; ++i; }
            int j = i + rem;

            float aa = 0.f, ab = 0.f, bb = 0.f;
            #pragma unroll 8
            for (int d = 0; d < D; ++d) {
                float ma = mush[d * K + i];
                float mb = mush[d * K + j];
                aa = fmaf(ma, ma, aa);
                ab = fmaf(ma, mb, ab);
                bb = fmaf(mb, mb, bb);
            }
            float q0 = bb;
            float q1 = 2.f * (ab - bb);
            float q2 = aa - 2.f * ab + bb;

            G0[t] = C0 + logpi - 0.5f * q0;
            G1[t] = -0.5f * q1;
            G2[t] = -0.5f * q2;    // <= 0 (concave in w)
            iA[t] = i;
            iB[t] = j;
        }
    }
    __syncthreads();                       // G*, iA/iB ready

    // ---- c[k] = z_b . mu[:,k]; group grp covers 16 d's for k = lane&15 ----
    const int grp = lane >> 4;
    const int kk = lane & 15;
    const int kkc = (kk < K) ? kk : (K - 1);
    const float* zw0 = &zsh[(wv << 1)][grp * 16];
    const float* zw1 = &zsh[(wv << 1) + 1][grp * 16];
    float c0 = 0.f, c1 = 0.f;
    #pragma unroll
    for (int i = 0; i < 16; ++i) {
        float m = mush[(grp * 16 + i) * K + kkc];   // shared between both samples
        c0 = fmaf(zw0[i], m, c0);
        c1 = fmaf(zw1[i], m, c1);
    }
    c0 += __shfl_xor(c0, 16); c0 += __shfl_xor(c0, 32);
    c1 += __shfl_xor(c1, 16); c1 += __shfl_xor(c1, 32);
    // lanes 0..14 hold c[0..14] for each sample

    // ---- per-s quadratics: s1 = lane, s2 = lane+64 (valid for lane<56) ----
    const int s1 = lane;
    const int s2 = lane + 64;
    const bool v2 = (s2 < S);
    const int s2c = v2 ? s2 : (S - 1);

    const int ia1 = iA[s1], ib1 = iB[s1];
    const int ia2 = iA[s2c], ib2 = iB[s2c];
    const float g01 = G0[s1], g11 = G1[s1], T21 = G2[s1];
    const float g02 = G0[s2c], g12 = G1[s2c], T22 = G2[s2c];

    float cA10 = __shfl(c0, ia1), cB10 = __shfl(c0, ib1);
    float cA20 = __shfl(c0, ia2), cB20 = __shfl(c0, ib2);
    float cA11 = __shfl(c1, ia1), cB11 = __shfl(c1, ib1);
    float cA21 = __shfl(c1, ia2), cB21 = __shfl(c1, ib2);

    // sample 0
    float T010 = g01 + cB10 - 0.5f * zz0;
    float T110 = g11 + (cA10 - cB10);
    float T020 = v2 ? (g02 + cB20 - 0.5f * zz0) : -1e30f;
    float T120 = g12 + (cA20 - cB20);
    // sample 1
    float T011 = g01 + cB11 - 0.5f * zz1;
    float T111 = g11 + (cA11 - cB11);
    float T021 = v2 ? (g02 + cB21 - 0.5f * zz1) : -1e30f;
    float T121 = g12 + (cA21 - cB21);

    // rcp of shared T2's (guarded inside qbound by T2<0; diagonal edges have T2==0)
    const float r21 = __builtin_amdgcn_rcpf(T21);
    const float r22 = __builtin_amdgcn_rcpf(T22);

    float bnd0 = fmaxf(qbound(T010, T110, T21, r21), qbound(T020, T120, T22, r22));
    float bnd1 = fmaxf(qbound(T011, T111, T21, r21), qbound(T021, T121, T22, r22));
    #pragma unroll
    for (int off = 32; off; off >>= 1) {
        bnd0 = fmaxf(bnd0, __shfl_xor(bnd0, off));
        bnd1 = fmaxf(bnd1, __shfl_xor(bnd1, off));
    }
    const float Mb0 = bnd0, Mb1 = bnd1;

    // ---- log2-domain coefficients ----
    const float a2_1 = T21 * L2E, a2_2 = T22 * L2E;       // shared across samples
    const float a0_10 = (T010 - Mb0) * L2E, a1_10 = T110 * L2E;
    const float a0_20 = (T020 - Mb0) * L2E, a1_20 = T120 * L2E;
    const float a0_11 = (T011 - Mb1) * L2E, a1_11 = T111 * L2E;
    const float a0_21 = (T021 - Mb1) * L2E, a1_21 = T121 * L2E;

    // Multiplicative recurrence from w=0.5 outward (see prior version's notes).
    const float h1 = fexp2(2.0e-4f * a2_1);               // shared across samples
    const float h2 = fexp2(2.0e-4f * a2_2);

    float e10 = fexp2(fmaf(0.5f, fmaf(0.5f, a2_1, a1_10), a0_10));
    float g10 = fexp2(fmaf(0.0101f, a2_1,  0.01f * a1_10));
    float d10 = fexp2(fmaf(-0.0099f, a2_1, -0.01f * a1_10));
    float e20 = fexp2(fmaf(0.5f, fmaf(0.5f, a2_2, a1_20), a0_20));
    float g20 = fexp2(fmaf(0.0101f, a2_2,  0.01f * a1_20));
    float d20 = fexp2(fmaf(-0.0099f, a2_2, -0.01f * a1_20));
    float e11 = fexp2(fmaf(0.5f, fmaf(0.5f, a2_1, a1_11), a0_11));
    float g11x = fexp2(fmaf(0.0101f, a2_1,  0.01f * a1_11));
    float d11 = fexp2(fmaf(-0.0099f, a2_1, -0.01f * a1_11));
    float e21 = fexp2(fmaf(0.5f, fmaf(0.5f, a2_2, a1_21), a0_21));
    float g21x = fexp2(fmaf(0.0101f, a2_2,  0.01f * a1_21));
    float d21 = fexp2(fmaf(-0.0099f, a2_2, -0.01f * a1_21));

    float eu10 = e10,       gu10 = g10,       ed10 = e10 * d10, du10 = d10 * h1;
    float eu20 = e20,       gu20 = g20,       ed20 = e20 * d20, du20 = d20 * h2;
    float eu11 = e11,       gu11 = g11x,      ed11 = e11 * d11, du11 = d11 * h1;
    float eu21 = e21,       gu21 = g21x,      ed21 = e21 * d21, du21 = d21 * h2;
    float su10 = 0.f, sd10 = 0.f, su20 = 0.f, sd20 = 0.f;
    float su11 = 0.f, sd11 = 0.f, su21 = 0.f, sd21 = 0.f;

    #pragma unroll 10
    for (int m = 0; m < 50; ++m) {
        su10 += eu10; eu10 *= gu10; gu10 *= h1;
        sd10 += ed10; ed10 *= du10; du10 *= h1;
        su20 += eu20; eu20 *= gu20; gu20 *= h2;
        sd20 += ed20; ed20 *= du20; du20 *= h2;
        su11 += eu11; eu11 *= gu11; gu11 *= h1;
        sd11 += ed11; ed11 *= du11; du11 *= h1;
        su21 += eu21; eu21 *= gu21; gu21 *= h2;
        sd21 += ed21; ed21 *= du21; du21 *= h2;
    }

    float ssum0 = (su10 + sd10) + (su20 + sd20);
    float ssum1 = (su11 + sd11) + (su21 + sd21);
    #pragma unroll
    for (int off = 32; off; off >>= 1) {
        ssum0 += __shfl_xor(ssum0, off);
        ssum1 += __shfl_xor(ssum1, off);
    }

    if (lane == 0) {
        bsum[(wv << 1)]     = Mb0 + flog2(ssum0) * INV_L2E;
        bsum[(wv << 1) + 1] = Mb1 + flog2(ssum1) * INV_L2E;
    }
    __syncthreads();
    if (t == 0) {
        float blk = (((bsum[0] + bsum[1]) + (bsum[2] + bsum[3]))
                   + ((bsum[4] + bsum[5]) + (bsum[6] + bsum[7]))
                   - 8.f * LOGM) * (1.0f / 4096.0f);
        atomicAdd(out, blk);
    }
}

extern "C" void kernel_launch(void* const* d_in, const int* in_sizes, int n_in,
                              void* d_out, int out_size, void* d_ws, size_t ws_size,
                              hipStream_t stream) {
    const float* z  = (const float*)d_in[0];   // [4096, 1, 64]
    const float* pi = (const float*)d_in[1];   // [1, 120]
    const float* mu = (const float*)d_in[2];   // [64, 15]
    float* out = (float*)d_out;                // scalar

    hipMemsetAsync(out, 0, sizeof(float), stream);  // graph-capturable memset node
    gmm_fused<<<512, 256, 0, stream>>>(z, pi, mu, out);
}

// Round 3
// 68.215 us; speedup vs baseline: 1.1140x; 1.0263x over previous
//
#include <hip/hip_runtime.h>
#include <math.h>
#include <float.h>

#define D 64
#define K 15
#define S 120          // K*(K+1)/2
#define MNUM 100
#define C0 (-58.81206612509905f)   // -0.5 * 64 * log(2*pi)
#define L2E 1.4426950408889634f
#define INV_L2E 0.6931471805599453f
#define LOGM 4.605170185988091f    // log(100)

static __device__ __forceinline__ float fexp2(float x) { return __builtin_amdgcn_exp2f(x); }
static __device__ __forceinline__ float flog2(float x) { return __builtin_amdgcn_logf(x); }

// Concave quadratic max over w in [0, 0.99]: T0 + T1*w + T2*w^2, T2 <= 0.
static __device__ __forceinline__ float qbound(float T0, float T1, float T2, float r2) {
    float bnd = fmaxf(T0, fmaf(0.99f, fmaf(0.99f, T2, T1), T0));
    if (T2 < 0.f) {
        float wx = fminf(fmaxf(-T1 * 0.5f * r2, 0.f), 0.99f);
        bnd = fmaxf(bnd, fmaf(wx, fmaf(wx, T2, T1), T0));
    }
    return bnd;
}

// Single fused kernel, 256 blocks x 256 threads, 4 samples per wave.
// vs R2 (512 blocks, 2 samples/wave): atomics 512->256, redundant setups
// halved, per-wave shared setup (G loads, mush reads, T2, rcp, h) amortized
// over 4 samples. 1 block/CU, 1 wave/SIMD: recurrence has 48 independent
// FMA chains/wave so issue stays saturated.
__global__ __launch_bounds__(256) void gmm_fused(const float* __restrict__ z,
                                                 const float* __restrict__ pi,
                                                 const float* __restrict__ mu,
                                                 float* __restrict__ out) {
    __shared__ float mush[D * K];          // mu staged: mu[d*K+k]
    __shared__ float G0[S], G1[S], G2[S];  // per-edge quadratic coeffs
    __shared__ int   iA[S], iB[S];
    __shared__ float zsh[16][D];
    __shared__ float bsum[16];

    const int t = threadIdx.x;
    const int lane = t & 63;
    const int wv = t >> 6;
    const int b0 = (blockIdx.x << 4) + (wv << 2);   // wave handles b0 .. b0+3

    // ---- z loads issued first (HBM latency hides under staging/setup) ----
    float zv[4], zz[4];
    #pragma unroll
    for (int j = 0; j < 4; ++j) zv[j] = z[(b0 + j) * D + lane];

    // ---- stage mu into LDS ----
    for (int i = t; i < D * K; i += 256) mush[i] = mu[i];

    // ---- wave-private zsh store + ||z||^2 (wave reads only its own rows) ----
    #pragma unroll
    for (int j = 0; j < 4; ++j) {
        zsh[(wv << 2) + j][lane] = zv[j];
        zz[j] = zv[j] * zv[j];
    }
    #pragma unroll
    for (int off = 32; off; off >>= 1) {
        #pragma unroll
        for (int j = 0; j < 4; ++j) zz[j] += __shfl_xor(zz[j], off);
    }

    __syncthreads();                       // mush fully staged

    // ---- setup on waves 0-1 only: shfl-only softmax + per-edge quadratics ----
    if (t < 128) {
        float pa = pi[lane];                                   // s = lane (< 120)
        float pb = (lane < S - 64) ? pi[lane + 64] : -FLT_MAX; // s = lane+64
        float mx = fmaxf(pa, pb);
        #pragma unroll
        for (int off = 32; off; off >>= 1) mx = fmaxf(mx, __shfl_xor(mx, off));
        float ea = fexp2((pa - mx) * L2E);
        float eb = (lane < S - 64) ? fexp2((pb - mx) * L2E) : 0.f;
        float se = ea + eb;
        #pragma unroll
        for (int off = 32; off; off >>= 1) se += __shfl_xor(se, off);

        if (t < S) {
            float e = wv ? eb : ea;            // wave0: s=lane, wave1: s=64+lane
            float logpi = logf(e / se + 1e-30f);  // matches ref log(softmax+1e-30)

            int i = 0, rem = t;
            while (rem >= K - i) { rem -= K - i; ++i; }
            int j = i + rem;

            float aa = 0.f, ab = 0.f, bb = 0.f;
            #pragma unroll 8
            for (int d = 0; d < D; ++d) {
                float ma = mush[d * K + i];
                float mb = mush[d * K + j];
                aa = fmaf(ma, ma, aa);
                ab = fmaf(ma, mb, ab);
                bb = fmaf(mb, mb, bb);
            }
            G0[t] = C0 + logpi - 0.5f * bb;
            G1[t] = -(ab - bb);                    // -0.5 * 2*(ab-bb)
            G2[t] = -0.5f * (aa - 2.f * ab + bb);  // <= 0 (concave in w)
            iA[t] = i;
            iB[t] = j;
        }
    }
    __syncthreads();                       // G*, iA/iB ready

    // ---- c[k] = z_b . mu[:,k]; group grp covers 16 d's for k = lane&15 ----
    const int grp = lane >> 4;
    const int kk = lane & 15;
    const int kkc = (kk < K) ? kk : (K - 1);
    float c[4] = {0.f, 0.f, 0.f, 0.f};
    {
        const float* zw0 = &zsh[(wv << 2) + 0][grp * 16];
        const float* zw1 = &zsh[(wv << 2) + 1][grp * 16];
        const float* zw2 = &zsh[(wv << 2) + 2][grp * 16];
        const float* zw3 = &zsh[(wv << 2) + 3][grp * 16];
        #pragma unroll
        for (int i = 0; i < 16; ++i) {
            float m = mush[(grp * 16 + i) * K + kkc];   // shared across 4 samples
            c[0] = fmaf(zw0[i], m, c[0]);
            c[1] = fmaf(zw1[i], m, c[1]);
            c[2] = fmaf(zw2[i], m, c[2]);
            c[3] = fmaf(zw3[i], m, c[3]);
        }
    }
    #pragma unroll
    for (int j = 0; j < 4; ++j) {
        c[j] += __shfl_xor(c[j], 16);
        c[j] += __shfl_xor(c[j], 32);
    }
    // lanes 0..14 hold c[0..14] for each sample

    // ---- per-s quadratics: s1 = lane, s2 = lane+64 (valid for lane<56) ----
    const int s1 = lane;
    const int s2 = lane + 64;
    const bool v2 = (s2 < S);
    const int s2c = v2 ? s2 : (S - 1);

    const int ia1 = iA[s1], ib1 = iB[s1];
    const int ia2 = iA[s2c], ib2 = iB[s2c];
    const float g01 = G0[s1], g11 = G1[s1], T21 = G2[s1];
    const float g02 = G0[s2c], g12 = G1[s2c], T22 = G2[s2c];

    // rcp of shared T2's (guarded inside qbound by T2<0)
    const float r21 = __builtin_amdgcn_rcpf(T21);
    const float r22 = __builtin_amdgcn_rcpf(T22);

    float T0a[4], T1a[4], T0b[4], T1b[4], Mb[4];
    #pragma unroll
    for (int j = 0; j < 4; ++j) {
        float cA1 = __shfl(c[j], ia1), cB1 = __shfl(c[j], ib1);
        float cA2 = __shfl(c[j], ia2), cB2 = __shfl(c[j], ib2);
        T0a[j] = g01 + cB1 - 0.5f * zz[j];
        T1a[j] = g11 + (cA1 - cB1);
        T0b[j] = v2 ? (g02 + cB2 - 0.5f * zz[j]) : -1e30f;
        T1b[j] = g12 + (cA2 - cB2);
        Mb[j] = fmaxf(qbound(T0a[j], T1a[j], T21, r21),
                      qbound(T0b[j], T1b[j], T22, r22));
    }
    #pragma unroll
    for (int off = 32; off; off >>= 1) {
        #pragma unroll
        for (int j = 0; j < 4; ++j) Mb[j] = fmaxf(Mb[j], __shfl_xor(Mb[j], off));
    }

    // ---- log2-domain coefficients; shared across samples: a2's and h's ----
    const float a2_1 = T21 * L2E, a2_2 = T22 * L2E;
    const float h1 = fexp2(2.0e-4f * a2_1);
    const float h2 = fexp2(2.0e-4f * a2_2);

    // Multiplicative recurrence from w=0.5 outward.
    // e_{m+1}/e_m = exp2(a1*d + a2*d^2*(2m+1)), ratio-of-ratios h = exp2(2*a2*d^2).
    // Concavity (a2<=0): outward decay monotone past vertex; init at mid is
    // within |a2|/4 log2-units of the peak (no spurious underflow).
    float eu1[4], gu1[4], ed1[4], du1[4], su1[4], sd1[4];
    float eu2[4], gu2[4], ed2[4], du2[4], su2[4], sd2[4];
    #pragma unroll
    for (int j = 0; j < 4; ++j) {
        const float a0a = (T0a[j] - Mb[j]) * L2E, a1a = T1a[j] * L2E;
        const float a0b = (T0b[j] - Mb[j]) * L2E, a1b = T1b[j] * L2E;
        float e1 = fexp2(fmaf(0.5f, fmaf(0.5f, a2_1, a1a), a0a));  // e at m=50
        float g1 = fexp2(fmaf(0.0101f, a2_1,  0.01f * a1a));       // e51/e50
        float d1 = fexp2(fmaf(-0.0099f, a2_1, -0.01f * a1a));      // e49/e50
        float e2 = fexp2(fmaf(0.5f, fmaf(0.5f, a2_2, a1b), a0b));
        float g2 = fexp2(fmaf(0.0101f, a2_2,  0.01f * a1b));
        float d2 = fexp2(fmaf(-0.0099f, a2_2, -0.01f * a1b));
        eu1[j] = e1;      gu1[j] = g1;
        ed1[j] = e1 * d1; du1[j] = d1 * h1;
        eu2[j] = e2;      gu2[j] = g2;
        ed2[j] = e2 * d2; du2[j] = d2 * h2;
        su1[j] = 0.f; sd1[j] = 0.f; su2[j] = 0.f; sd2[j] = 0.f;
    }

    #pragma unroll 5
    for (int m = 0; m < 50; ++m) {
        #pragma unroll
        for (int j = 0; j < 4; ++j) {
            su1[j] += eu1[j]; eu1[j] *= gu1[j]; gu1[j] *= h1;   // e_50 .. e_99
            sd1[j] += ed1[j]; ed1[j] *= du1[j]; du1[j] *= h1;   // e_49 .. e_0
            su2[j] += eu2[j]; eu2[j] *= gu2[j]; gu2[j] *= h2;
            sd2[j] += ed2[j]; ed2[j] *= du2[j]; du2[j] *= h2;
        }
    }

    float ssum[4];
    #pragma unroll
    for (int j = 0; j < 4; ++j) ssum[j] = (su1[j] + sd1[j]) + (su2[j] + sd2[j]);
    #pragma unroll
    for (int off = 32; off; off >>= 1) {
        #pragma unroll
        for (int j = 0; j < 4; ++j) ssum[j] += __shfl_xor(ssum[j], off);
    }

    if (lane == 0) {
        #pragma unroll
        for (int j = 0; j < 4; ++j)
            bsum[(wv << 2) + j] = Mb[j] + flog2(ssum[j]) * INV_L2E;
    }
    __syncthreads();

    // ---- lane-parallel block reduce of 16 partials -> one atomicAdd ----
    if (wv == 0) {
        float v = (lane < 16) ? bsum[lane] : 0.f;
        v += __shfl_xor(v, 8);
        v += __shfl_xor(v, 4);
        v += __shfl_xor(v, 2);
        v += __shfl_xor(v, 1);
        if (lane == 0)
            atomicAdd(out, (v - 16.f * LOGM) * (1.0f / 4096.0f));
    }
}

extern "C" void kernel_launch(void* const* d_in, const int* in_sizes, int n_in,
                              void* d_out, int out_size, void* d_ws, size_t ws_size,
                              hipStream_t stream) {
    const float* z  = (const float*)d_in[0];   // [4096, 1, 64]
    const float* pi = (const float*)d_in[1];   // [1, 120]
    const float* mu = (const float*)d_in[2];   // [64, 15]
    float* out = (float*)d_out;                // scalar

    hipMemsetAsync(out, 0, sizeof(float), stream);  // graph-capturable memset node
    gmm_fused<<<256, 256, 0, stream>>>(z, pi, mu, out);
}